// Round 1
// baseline (4868.053 us; speedup 1.0000x reference)
//
#include <hip/hip_runtime.h>
#include <hip/hip_bf16.h>

typedef __attribute__((ext_vector_type(8))) short short8;
typedef __attribute__((ext_vector_type(4))) float floatx4;
typedef __hip_bfloat16 bf16;

#define MFMA16(a,b,c) __builtin_amdgcn_mfma_f32_16x16x32_bf16((a),(b),(c),0,0,0)

__device__ __forceinline__ short8 ldf(const bf16* p){ return *(const short8*)p; }
__device__ __forceinline__ float fsig(float x){ return 1.f/(1.f+__expf(-x)); }
__device__ __forceinline__ float ftanh(float x){
  float c = fminf(fmaxf(x,-15.f),15.f);
  float e = __expf(2.f*c);
  return (e-1.f)/(e+1.f);
}

// ---------------- weight prep: fp32 [R][C] -> bf16 [C][R] ----------------
__global__ __launch_bounds__(256) void k_transpose(const float* __restrict__ in,
                                                   bf16* __restrict__ out, int R, int C){
  __shared__ float t[32][33];
  int bc = blockIdx.x*32, br = blockIdx.y*32;
  int tx = threadIdx.x & 31, ty = threadIdx.x >> 5; // 32 x 8
  #pragma unroll
  for (int i=0;i<32;i+=8) t[ty+i][tx] = in[(size_t)(br+ty+i)*C + bc+tx];
  __syncthreads();
  #pragma unroll
  for (int i=0;i<32;i+=8) out[(size_t)(bc+ty+i)*R + br+tx] = __float2bfloat16(t[tx][ty+i]);
}

__global__ __launch_bounds__(256) void k_cast(const float* __restrict__ in, bf16* __restrict__ out, int n){
  int i = blockIdx.x*256+threadIdx.x;
  if (i<n) out[i] = __float2bfloat16(in[i]);
}

// state [256,64] -> PIN cols 0:64 (PIN row stride 192)
__global__ __launch_bounds__(256) void k_cast_state(const float* __restrict__ st, bf16* __restrict__ pin){
  int i = blockIdx.x*256+threadIdx.x; // 16384
  int r = i >> 6, c = i & 63;
  pin[r*192 + c] = __float2bfloat16(st[i]);
}

// act MLP hidden: H1[(t*256+b)][c] = tanh(sum_i act[b][t][i]*w1[i][c] + b1[c])
__global__ __launch_bounds__(256) void k_acth1(const float* __restrict__ act,
                                               const float* __restrict__ w1,
                                               const float* __restrict__ b1,
                                               bf16* __restrict__ H1){
  int idx = blockIdx.x*256 + threadIdx.x;          // 16384*512
  int c = idx & 511; int r = idx >> 9;             // r = t*256+b
  int t = r >> 8, b = r & 255;
  const float* a = act + (b*64 + t)*6;
  float s = b1[c];
  #pragma unroll
  for (int i=0;i<6;i++) s += a[i]*w1[i*512+c];
  H1[r*512+c] = __float2bfloat16(ftanh(s));
}

// ---------------- generic GEMM: out[m][j] = act(A[m,:K] . Bt[j,:K] + bias[j]) ----------------
// wave tile 16x16; grid (N/64, M/16); block 256
__global__ __launch_bounds__(256) void k_gemm16(
  const bf16* __restrict__ A, int sA,
  const bf16* __restrict__ Bt,
  const float* __restrict__ bias,
  bf16* __restrict__ out, int sO, int oO,
  int K, int mode)
{
  int lane = threadIdx.x & 63, wave = threadIdx.x >> 6;
  int lr = lane & 15, lq = lane >> 4;
  int j0 = blockIdx.x*64 + wave*16;
  int m0 = blockIdx.y*16;
  const bf16* Ap = A + (m0+lr)*sA + lq*8;
  const bf16* Bp = Bt + (j0+lr)*K + lq*8;
  floatx4 acc = {0.f,0.f,0.f,0.f};
  #pragma unroll 4
  for (int kb=0; kb<K; kb+=32){
    short8 a = ldf(Ap+kb);
    short8 b = ldf(Bp+kb);
    acc = MFMA16(a, b, acc);
  }
  #pragma unroll
  for (int i=0;i<4;i++){
    int m = m0 + lq*4 + i, j = j0 + lr;
    float v = acc[i] + bias[j];
    if (mode) v = ftanh(v);
    out[m*sO + oO + j] = __float2bfloat16(v);
  }
}

// ---------------- gaussian head: z = mu + exp(ls)*eps ; Bt has 2048 rows (mu: j, ls: j+1024) ----------------
// grid (16,16), block 256, M=256, N=1024
__global__ __launch_bounds__(256) void k_gauss(
  const bf16* __restrict__ A, const bf16* __restrict__ Bt,
  const float* __restrict__ bias, const float* __restrict__ eps,
  bf16* __restrict__ out, int K)
{
  int lane = threadIdx.x & 63, wave = threadIdx.x >> 6;
  int lr = lane & 15, lq = lane >> 4;
  int j0 = blockIdx.x*64 + wave*16;
  int m0 = blockIdx.y*16;
  const bf16* Ap = A + (m0+lr)*K + lq*8;
  const bf16* Bm = Bt + (j0+lr)*K + lq*8;
  const bf16* Bl = Bt + (j0+1024+lr)*K + lq*8;
  floatx4 aM = {0.f,0.f,0.f,0.f}, aL = {0.f,0.f,0.f,0.f};
  #pragma unroll 4
  for (int kb=0;kb<K;kb+=32){
    short8 a = ldf(Ap+kb);
    aM = MFMA16(a, ldf(Bm+kb), aM);
    aL = MFMA16(a, ldf(Bl+kb), aL);
  }
  #pragma unroll
  for (int i=0;i<4;i++){
    int m = m0+lq*4+i, j = j0+lr;
    float z = aM[i] + bias[j] + __expf(aL[i] + bias[1024+j]) * eps[m*1024 + j];
    out[m*1024+j] = __float2bfloat16(z);
  }
}

// ---------------- fused GRU step ----------------
// grid 256 (wg>>4 = row tile, wg&15 + wave = j tile), block 256
__global__ __launch_bounds__(256) void k_gru(
  const bf16* __restrict__ Z, const bf16* __restrict__ H, const bf16* __restrict__ AEt,
  const bf16* __restrict__ WzT, const bf16* __restrict__ WhT, const bf16* __restrict__ WaT,
  const float* __restrict__ bih, const float* __restrict__ bhh,
  bf16* __restrict__ Hout)
{
  int lane = threadIdx.x & 63, wave = threadIdx.x >> 6;
  int lr = lane & 15, lq = lane >> 4;
  int wg = blockIdx.x;
  int m0 = (wg >> 4) * 16;
  int j0 = ((wg & 15)*4 + wave) * 16;

  floatx4 aR = {0.f,0.f,0.f,0.f}, aU = aR, aN = aR, aHN = aR;
  { // phase z: K=1024
    const bf16* Ap = Z + (m0+lr)*1024 + lq*8;
    const bf16* Br = WzT + (j0+lr)*1024 + lq*8;
    const bf16* Bu = WzT + (j0+1024+lr)*1024 + lq*8;
    const bf16* Bn = WzT + (j0+2048+lr)*1024 + lq*8;
    #pragma unroll 4
    for (int kb=0; kb<1024; kb+=32){
      short8 a = ldf(Ap+kb);
      aR = MFMA16(a, ldf(Br+kb), aR);
      aU = MFMA16(a, ldf(Bu+kb), aU);
      aN = MFMA16(a, ldf(Bn+kb), aN);
    }
  }
  { // phase h: K=1024
    const bf16* Ap = H + (m0+lr)*1024 + lq*8;
    const bf16* Br = WhT + (j0+lr)*1024 + lq*8;
    const bf16* Bu = WhT + (j0+1024+lr)*1024 + lq*8;
    const bf16* Bn = WhT + (j0+2048+lr)*1024 + lq*8;
    #pragma unroll 4
    for (int kb=0; kb<1024; kb+=32){
      short8 a = ldf(Ap+kb);
      aR = MFMA16(a, ldf(Br+kb), aR);
      aU = MFMA16(a, ldf(Bu+kb), aU);
      aHN = MFMA16(a, ldf(Bn+kb), aHN);
    }
  }
  { // phase ae: K=512
    const bf16* Ap = AEt + (m0+lr)*512 + lq*8;
    const bf16* Br = WaT + (j0+lr)*512 + lq*8;
    const bf16* Bu = WaT + (j0+1024+lr)*512 + lq*8;
    const bf16* Bn = WaT + (j0+2048+lr)*512 + lq*8;
    #pragma unroll 4
    for (int kb=0; kb<512; kb+=32){
      short8 a = ldf(Ap+kb);
      aR = MFMA16(a, ldf(Br+kb), aR);
      aU = MFMA16(a, ldf(Bu+kb), aU);
      aN = MFMA16(a, ldf(Bn+kb), aN);
    }
  }
  #pragma unroll
  for (int i=0;i<4;i++){
    int m = m0 + lq*4 + i, j = j0 + lr;
    float r = fsig(aR[i] + bih[j] + bhh[j]);
    float u = fsig(aU[i] + bih[1024+j] + bhh[1024+j]);
    float n = ftanh(aN[i] + bih[2048+j] + r*(aHN[i] + bhh[2048+j]));
    float h = __bfloat162float(H[m*1024+j]);
    Hout[m*1024+j] = __float2bfloat16((1.f-u)*n + u*h);
  }
}

// ---------------- decode: Y1 = tanh(din @ dec_w1 + b) ----------------
// din row m (= t*256+b): k<1024 -> Zbuf[(m+256)*1024+k], else Hbuf[(m+256)*1024+k-1024]
// grid (4, 512), block 256; wave tile 32x64
__global__ __launch_bounds__(256) void k_dec1(
  const bf16* __restrict__ Zb, const bf16* __restrict__ Hb,
  const bf16* __restrict__ W, const float* __restrict__ bias,
  bf16* __restrict__ Y)
{
  int lane = threadIdx.x & 63, wave = threadIdx.x >> 6;
  int lr = lane & 15, lq = lane >> 4;
  int m0 = blockIdx.y * 32;
  int j0 = blockIdx.x * 256 + wave * 64;
  floatx4 acc[2][4] = {};
  for (int kb=0; kb<2048; kb+=32){
    const bf16* Abase = kb < 1024 ? (Zb + 256*1024 + kb) : (Hb + 256*1024 + (kb-1024));
    short8 a0 = ldf(Abase + (m0+lr)*1024 + lq*8);
    short8 a1 = ldf(Abase + (m0+16+lr)*1024 + lq*8);
    #pragma unroll
    for (int c=0;c<4;c++){
      short8 b = ldf(W + (j0+c*16+lr)*2048 + kb + lq*8);
      acc[0][c] = MFMA16(a0,b,acc[0][c]);
      acc[1][c] = MFMA16(a1,b,acc[1][c]);
    }
  }
  #pragma unroll
  for (int rf=0;rf<2;rf++)
    #pragma unroll
    for (int c=0;c<4;c++)
      #pragma unroll
      for (int i=0;i<4;i++){
        int m = m0 + rf*16 + lq*4 + i;
        int j = j0 + c*16 + lr;
        Y[m*1024 + j] = __float2bfloat16(ftanh(acc[rf][c][i] + bias[j]));
      }
}

// obs_pred = Y1 @ dec_w2 + b -> out[b][t][0:512]; grid (2,512), wave 32x64
__global__ __launch_bounds__(256) void k_out1(
  const bf16* __restrict__ Y, const bf16* __restrict__ W, const float* __restrict__ bias,
  float* __restrict__ out)
{
  int lane = threadIdx.x & 63, wave = threadIdx.x >> 6;
  int lr = lane & 15, lq = lane >> 4;
  int m0 = blockIdx.y * 32;
  int j0 = blockIdx.x * 256 + wave * 64;
  floatx4 acc[2][4] = {};
  for (int kb=0; kb<1024; kb+=32){
    short8 a0 = ldf(Y + (m0+lr)*1024 + kb + lq*8);
    short8 a1 = ldf(Y + (m0+16+lr)*1024 + kb + lq*8);
    #pragma unroll
    for (int c=0;c<4;c++){
      short8 b = ldf(W + (j0+c*16+lr)*1024 + kb + lq*8);
      acc[0][c] = MFMA16(a0,b,acc[0][c]);
      acc[1][c] = MFMA16(a1,b,acc[1][c]);
    }
  }
  #pragma unroll
  for (int rf=0;rf<2;rf++)
    #pragma unroll
    for (int c=0;c<4;c++)
      #pragma unroll
      for (int i=0;i<4;i++){
        int m = m0 + rf*16 + lq*4 + i;
        int j = j0 + c*16 + lr;
        int b = m & 255, t = m >> 8;
        out[b*40960 + t*640 + j] = acc[rf][c][i] + bias[j];
      }
}

// state decoder: din @ sd_w + b -> out[...,512:576]=mu, [...,576:640]=exp(ls)
// grid 512, block 256; wave: 32 rows x 16 j (wave = j tile)
__global__ __launch_bounds__(256) void k_sd(
  const bf16* __restrict__ Zb, const bf16* __restrict__ Hb,
  const bf16* __restrict__ W, const float* __restrict__ bias,
  float* __restrict__ out)
{
  int lane = threadIdx.x & 63, wave = threadIdx.x >> 6;
  int lr = lane & 15, lq = lane >> 4;
  int m0 = blockIdx.x * 32;
  int j0 = wave * 16;
  floatx4 aM[2] = {}, aL[2] = {};
  for (int kb=0; kb<2048; kb+=32){
    const bf16* Abase = kb < 1024 ? (Zb + 256*1024 + kb) : (Hb + 256*1024 + (kb-1024));
    short8 a0 = ldf(Abase + (m0+lr)*1024 + lq*8);
    short8 a1 = ldf(Abase + (m0+16+lr)*1024 + lq*8);
    short8 bm = ldf(W + (j0+lr)*2048 + kb + lq*8);
    short8 bl = ldf(W + (j0+64+lr)*2048 + kb + lq*8);
    aM[0] = MFMA16(a0,bm,aM[0]); aM[1] = MFMA16(a1,bm,aM[1]);
    aL[0] = MFMA16(a0,bl,aL[0]); aL[1] = MFMA16(a1,bl,aL[1]);
  }
  #pragma unroll
  for (int rf=0;rf<2;rf++)
    #pragma unroll
    for (int i=0;i<4;i++){
      int m = m0 + rf*16 + lq*4 + i;
      int j = j0 + lr;
      int b = m & 255, t = m >> 8;
      out[b*40960 + t*640 + 512 + j] = aM[rf][i] + bias[j];
      out[b*40960 + t*640 + 576 + j] = __expf(aL[rf][i] + bias[64+j]);
    }
}

extern "C" void kernel_launch(void* const* d_in, const int* in_sizes, int n_in,
                              void* d_out, int out_size, void* d_ws, size_t ws_size,
                              hipStream_t stream)
{
  const float* obs    = (const float*)d_in[0];
  const float* state  = (const float*)d_in[1];
  const float* act    = (const float*)d_in[2];
  const float* eps0   = (const float*)d_in[3];
  const float* epss   = (const float*)d_in[4];
  const float* enc_w1 = (const float*)d_in[5];  const float* enc_b1 = (const float*)d_in[6];
  const float* enc_w2 = (const float*)d_in[7];  const float* enc_b2 = (const float*)d_in[8];
  const float* post_w1= (const float*)d_in[9];  const float* post_b1= (const float*)d_in[10];
  const float* post_w2= (const float*)d_in[11]; const float* post_b2= (const float*)d_in[12];
  const float* amlp_w1= (const float*)d_in[13]; const float* amlp_b1= (const float*)d_in[14];
  const float* amlp_w2= (const float*)d_in[15]; const float* amlp_b2= (const float*)d_in[16];
  const float* gwih   = (const float*)d_in[17];
  const float* gwhh   = (const float*)d_in[18];
  const float* gbih   = (const float*)d_in[19];
  const float* gbhh   = (const float*)d_in[20];
  const float* lsd_w1 = (const float*)d_in[21]; const float* lsd_b1 = (const float*)d_in[22];
  const float* lsd_w2 = (const float*)d_in[23]; const float* lsd_b2 = (const float*)d_in[24];
  const float* dec_w1 = (const float*)d_in[25]; const float* dec_b1 = (const float*)d_in[26];
  const float* dec_w2 = (const float*)d_in[27]; const float* dec_b2 = (const float*)d_in[28];
  const float* sd_w   = (const float*)d_in[29]; const float* sd_b   = (const float*)d_in[30];
  float* out = (float*)d_out;

  char* w = (char*)d_ws;
  size_t off = 0;
  auto alloc = [&](size_t elems)->bf16* {
    bf16* p = (bf16*)(w + off);
    off += ((elems*2 + 255)/256)*256;
    return p;
  };
  bf16* WzT      = alloc((size_t)3072*1024);
  bf16* WhT      = alloc((size_t)3072*1024);
  bf16* WaT      = alloc((size_t)3072*512);
  bf16* lsd_w1T  = alloc((size_t)1024*1024);
  bf16* lsd_w2T  = alloc((size_t)2048*1024);
  bf16* dec_w1T  = alloc((size_t)1024*2048);
  bf16* dec_w2T  = alloc((size_t)512*1024);
  bf16* sd_wT    = alloc((size_t)128*2048);
  bf16* enc_w1T  = alloc((size_t)512*512);
  bf16* enc_w2T  = alloc((size_t)256*512);
  bf16* post_w1sT= alloc((size_t)1024*192);
  bf16* post_w2T = alloc((size_t)2048*1024);
  bf16* amlp_w2T = alloc((size_t)512*512);
  bf16* obsb     = alloc((size_t)256*512);
  bf16* E1       = alloc((size_t)256*512);
  bf16* PIN      = alloc((size_t)256*192);
  bf16* P1       = alloc((size_t)256*1024);
  bf16* X        = alloc((size_t)256*1024);
  bf16* Zbuf     = alloc((size_t)65*256*1024);
  bf16* Hbuf     = alloc((size_t)65*256*1024);
  bf16* AEb      = alloc((size_t)16384*512);
  bf16* Y1       = alloc((size_t)16384*1024);   // 32 MiB
  bf16* H1       = Y1;                          // H1 (16 MiB) dead before Y1 is written

  // --- weight prep (transpose fp32 [R][C] -> bf16 [C][R]) ---
  #define TP(src, dst, R, C) k_transpose<<<dim3((C)/32,(R)/32),256,0,stream>>>((src),(dst),(R),(C))
  TP(enc_w1, enc_w1T, 512, 512);
  TP(enc_w2, enc_w2T, 512, 256);
  TP(post_w1 + (size_t)1024*1024, post_w1sT, 192, 1024);
  TP(post_w2, post_w2T, 1024, 2048);
  TP(amlp_w2, amlp_w2T, 512, 512);
  TP(gwih, WzT, 1024, 3072);
  TP(gwih + (size_t)1024*3072, WaT, 512, 3072);
  TP(gwhh, WhT, 1024, 3072);
  TP(lsd_w1, lsd_w1T, 1024, 1024);
  TP(lsd_w2, lsd_w2T, 1024, 2048);
  TP(dec_w1, dec_w1T, 2048, 1024);
  TP(dec_w2, dec_w2T, 1024, 512);
  TP(sd_w, sd_wT, 2048, 128);
  #undef TP

  k_cast<<<512,256,0,stream>>>(obs, obsb, 256*512);
  k_cast_state<<<64,256,0,stream>>>(state, PIN);
  k_acth1<<<32768,256,0,stream>>>(act, amlp_w1, amlp_b1, H1);

  // h0 = 0
  hipMemsetAsync(Hbuf, 0, (size_t)256*1024*2, stream);

  // encoder: E1 = tanh(obs@enc_w1+b1); enc_mu = E1@enc_w2[:, :128]+b2 -> PIN cols 64:192
  k_gemm16<<<dim3(8,16),256,0,stream>>>(obsb, 512, enc_w1T, enc_b1, E1, 512, 0, 512, 1);
  k_gemm16<<<dim3(2,16),256,0,stream>>>(E1, 512, enc_w2T, enc_b2, PIN, 192, 64, 512, 0);
  // posterior: P1 = tanh(PIN@post_w1[1024:1216]+b1); z0 = mu + exp(ls)*eps0
  k_gemm16<<<dim3(16,16),256,0,stream>>>(PIN, 192, post_w1sT, post_b1, P1, 1024, 0, 192, 1);
  k_gauss<<<dim3(16,16),256,0,stream>>>(P1, post_w2T, post_b2, eps0, Zbuf, 1024);
  // AE = H1 @ amlp_w2 + b2  (linear)
  k_gemm16<<<dim3(8,1024),256,0,stream>>>(H1, 512, amlp_w2T, amlp_b2, AEb, 512, 0, 512, 0);

  // --- sequential scan ---
  for (int t=0; t<64; t++){
    const bf16* Zt = Zbuf + (size_t)t*256*1024;
    const bf16* Ht = Hbuf + (size_t)t*256*1024;
    bf16* Htn = Hbuf + (size_t)(t+1)*256*1024;
    bf16* Ztn = Zbuf + (size_t)(t+1)*256*1024;
    k_gru<<<256,256,0,stream>>>(Zt, Ht, AEb + (size_t)t*256*512, WzT, WhT, WaT, gbih, gbhh, Htn);
    k_gemm16<<<dim3(16,16),256,0,stream>>>(Htn, 1024, lsd_w1T, lsd_b1, X, 1024, 0, 1024, 1);
    k_gauss<<<dim3(16,16),256,0,stream>>>(X, lsd_w2T, lsd_b2, epss + (size_t)t*256*1024, Ztn, 1024);
  }

  // --- decode ---
  k_dec1<<<dim3(4,512),256,0,stream>>>(Zbuf, Hbuf, dec_w1T, dec_b1, Y1);
  k_out1<<<dim3(2,512),256,0,stream>>>(Y1, dec_w2T, dec_b2, out);
  k_sd<<<512,256,0,stream>>>(Zbuf, Hbuf, sd_wT, sd_b, out);
}